// Round 10
// baseline (299.336 us; speedup 1.0000x reference)
//
#include <hip/hip_runtime.h>
#include <cstddef>
#include <cstdint>

#define HIDV 256
#define KR 64
#define NH 4

typedef float f4 __attribute__((ext_vector_type(4)));
typedef short bh8 __attribute__((ext_vector_type(8)));   // 8 bf16 (raw bits)
typedef unsigned int u32;

#define MFMA16(a,b,c) __builtin_amdgcn_mfma_f32_16x16x32_bf16(a,b,c,0,0,0)

__device__ __forceinline__ float dotf4(f4 a, f4 b) {
  return a.x*b.x + a.y*b.y + a.z*b.z + a.w*b.w;
}
__device__ __forceinline__ f4 ntload4(const float* p) {
  return __builtin_nontemporal_load(reinterpret_cast<const f4*>(p));
}
template<int CTRL>
__device__ __forceinline__ float dppadd(float v) {
  int m = __builtin_amdgcn_update_dpp(0, __float_as_int(v), CTRL, 0xf, 0xf, true);
  return v + __int_as_float(m);
}
__device__ __forceinline__ float red64f(float v) {
  v = dppadd<0xB1>(v);
  v = dppadd<0x4E>(v);
  v = dppadd<0x124>(v);
  v = dppadd<0x128>(v);
  v += __shfl_xor(v, 16);
  v += __shfl_xor(v, 32);
  return v;
}
__device__ __forceinline__ u32 pk2(float a, float b) {
  u32 r;
  asm("v_cvt_pk_bf16_f32 %0, %1, %2" : "=v"(r) : "v"(a), "v"(b));
  return r;
}
__device__ __forceinline__ bh8 cvt8(f4 lo, f4 hi) {
  union { bh8 b; u32 u[4]; } r;
  r.u[0] = pk2(lo.x, lo.y); r.u[1] = pk2(lo.z, lo.w);
  r.u[2] = pk2(hi.x, hi.y); r.u[3] = pk2(hi.z, hi.w);
  return r.b;
}

// ---------- prep: pack weights into MFMA B-fragment-linear bf16 (byte-identical R9) ----------
__global__ __launch_bounds__(256) void k_prep_w(
    const float* __restrict__ ipw, const float* __restrict__ w_ad1,
    const float* __restrict__ w_im1, const float* __restrict__ opw,
    unsigned short* __restrict__ WQF, unsigned short* __restrict__ WKF,
    unsigned short* __restrict__ AD1F, unsigned short* __restrict__ IM1F,
    unsigned short* __restrict__ WVF, unsigned short* __restrict__ OPF)
{
  int f = blockIdx.x*256 + threadIdx.x;
  if (f >= 53248) return;
  const int l = f & 63, lr = l & 15, lk = l >> 4;
  int g = f >> 6;
  const float* src; unsigned short* dst; int stride; int gl;
  if (g < 128) {
    gl = g; int nt = g >> 3, s = g & 7;
    src = ipw + (size_t)(nt*16+lr)*256 + s*32 + lk*8; stride = 1; dst = WQF;
  } else if (g < 256) {
    gl = g - 128; int ntg = gl >> 1, s = gl & 1; int h = ntg >> 4, ntl = ntg & 15;
    src = ipw + 65536 + (size_t)(h*64 + s*32 + lk*8)*256 + ntl*16 + lr; stride = 256; dst = WKF;
  } else if (g < 320) {
    gl = g - 256; int nt = gl >> 3, s = gl & 7;
    src = w_ad1 + (size_t)(nt*16+lr)*256 + s*32 + lk*8; stride = 1; dst = AD1F;
  } else if (g < 576) {
    gl = g - 320; int nt = gl >> 4, s = gl & 15;
    src = w_im1 + (size_t)(nt*16+lr)*512 + s*32 + lk*8; stride = 1; dst = IM1F;
  } else if (g < 704) {
    gl = g - 576; int nt = gl >> 3, s = gl & 7;
    src = ipw + 131072 + (size_t)(nt*16+lr)*256 + s*32 + lk*8; stride = 1; dst = WVF;
  } else {
    gl = g - 704; int nt = gl >> 3, s = gl & 7;
    src = opw + (size_t)(nt*16+lr)*256 + s*32 + lk*8; stride = 1; dst = OPF;
  }
  float v[8];
  #pragma unroll
  for (int j = 0; j < 8; ++j) v[j] = src[(size_t)j*stride];
  union { bh8 b; u32 u[4]; } r;
  r.u[0] = pk2(v[0], v[1]); r.u[1] = pk2(v[2], v[3]);
  r.u[2] = pk2(v[4], v[5]); r.u[3] = pk2(v[6], v[7]);
  *reinterpret_cast<bh8*>(dst + ((size_t)gl*64 + l)*8) = r.b;
}

// ---------- prep: msg fp32 -> bf16 (byte-identical R9) ----------
__global__ __launch_bounds__(256) void k_prep_msg(
    const float* __restrict__ msg, unsigned short* __restrict__ msgb, int n8)
{
  int i = blockIdx.x*256 + threadIdx.x;
  if (i >= n8) return;
  const float* p = msg + (size_t)i*8;
  f4 lo = *reinterpret_cast<const f4*>(p);
  f4 hi = *reinterpret_cast<const f4*>(p+4);
  union { bh8 b; u32 u[4]; } r;
  r.u[0] = pk2(lo.x, lo.y); r.u[1] = pk2(lo.z, lo.w);
  r.u[2] = pk2(hi.x, hi.y); r.u[3] = pk2(hi.z, hi.w);
  *reinterpret_cast<bh8*>(msgb + (size_t)i*8) = r.b;
}

// ---------------- K0 (MFMA): q, qk, learned anomaly (byte-identical R9) ----------------
__global__ __launch_bounds__(256) void k0_mfma(
    const unsigned short* __restrict__ msgb,
    const float* __restrict__ ipb, const float* __restrict__ b_ad1,
    const float* __restrict__ w_ad2, const float* __restrict__ b_ad2,
    const unsigned short* __restrict__ WQF, const unsigned short* __restrict__ WKF,
    const unsigned short* __restrict__ AD1F,
    float* __restrict__ qk_ws, float* __restrict__ la_ws, int B)
{
  __shared__ float q_lds[16][260];
  __shared__ float part_ad[4][16];
  const int t = threadIdx.x, l = t & 63, w = t >> 6;
  const int lr = l & 15, lk = l >> 4;
  const int b0 = blockIdx.x * 16;

  const unsigned short* arow = msgb + (size_t)(b0 + lr) * HIDV;
  bh8 aM[8];
  #pragma unroll
  for (int s = 0; s < 8; ++s)
    aM[s] = *reinterpret_cast<const bh8*>(arow + s*32 + lk*8);

  f4 qa[4];
  #pragma unroll
  for (int n = 0; n < 4; ++n) {
    float bq = ipb[w*64 + n*16 + lr];
    f4 v = {bq, bq, bq, bq};
    qa[n] = v;
  }
  #pragma unroll
  for (int s = 0; s < 8; ++s) {
    #pragma unroll
    for (int n = 0; n < 4; ++n) {
      bh8 bw = *reinterpret_cast<const bh8*>(WQF + (((size_t)(w*4+n)*8 + s)*64 + l)*8);
      qa[n] = MFMA16(aM[s], bw, qa[n]);
    }
  }

  f4 ha[2];
  #pragma unroll
  for (int n = 0; n < 2; ++n) {
    float bb = b_ad1[w*32 + n*16 + lr];
    f4 v = {bb, bb, bb, bb};
    ha[n] = v;
  }
  #pragma unroll
  for (int s = 0; s < 8; ++s) {
    #pragma unroll
    for (int n = 0; n < 2; ++n) {
      bh8 bw = *reinterpret_cast<const bh8*>(AD1F + (((size_t)(w*2+n)*8 + s)*64 + l)*8);
      ha[n] = MFMA16(aM[s], bw, ha[n]);
    }
  }

  #pragma unroll
  for (int n = 0; n < 4; ++n)
    #pragma unroll
    for (int qq = 0; qq < 4; ++qq)
      q_lds[lk*4+qq][w*64 + n*16 + lr] = qa[n][qq];

  {
    float wa0 = w_ad2[w*32 + lr];
    float wa1 = w_ad2[w*32 + 16 + lr];
    float vv[4];
    #pragma unroll
    for (int qq = 0; qq < 4; ++qq)
      vv[qq] = fmaxf(ha[0][qq], 0.f)*wa0 + fmaxf(ha[1][qq], 0.f)*wa1;
    #pragma unroll
    for (int m = 1; m < 16; m <<= 1) {
      #pragma unroll
      for (int qq = 0; qq < 4; ++qq) vv[qq] += __shfl_xor(vv[qq], m, 64);
    }
    if (lr == 0) {
      #pragma unroll
      for (int qq = 0; qq < 4; ++qq) part_ad[w][lk*4+qq] = vv[qq];
    }
  }
  __syncthreads();
  if (t < 16) {
    float x = part_ad[0][t]+part_ad[1][t]+part_ad[2][t]+part_ad[3][t] + b_ad2[0];
    la_ws[b0 + t] = 1.f / (1.f + expf(-x));
  }

  const float* qrow = &q_lds[lr][0];
  for (int h = 0; h < NH; ++h) {
    f4 ka[4];
    #pragma unroll
    for (int n = 0; n < 4; ++n) { f4 z = {0.f,0.f,0.f,0.f}; ka[n] = z; }
    #pragma unroll
    for (int s2 = 0; s2 < 2; ++s2) {
      int k0 = h*64 + s2*32 + lk*8;
      f4 lo = *reinterpret_cast<const f4*>(qrow + k0);
      f4 hi = *reinterpret_cast<const f4*>(qrow + k0 + 4);
      bh8 aQ = cvt8(lo, hi);
      #pragma unroll
      for (int n = 0; n < 4; ++n) {
        bh8 bw = *reinterpret_cast<const bh8*>(WKF + (((size_t)((h*16 + w*4+n)*2 + s2))*64 + l)*8);
        ka[n] = MFMA16(aQ, bw, ka[n]);
      }
    }
    #pragma unroll
    for (int n = 0; n < 4; ++n)
      #pragma unroll
      for (int qq = 0; qq < 4; ++qq)
        qk_ws[(size_t)(b0 + lk*4 + qq)*(NH*HIDV) + h*HIDV + w*64 + n*16 + lr] = ka[n][qq];
  }
}

// ---------------- K1: single change vs R9 — upd stores are NORMAL (not NT) ----------------
__global__ __launch_bounds__(256) void k1_stream(
    const float* __restrict__ storage, const float* __restrict__ msg,
    const float* __restrict__ qk_ws,
    float* __restrict__ upd,
    float* __restrict__ mean_ws, float* __restrict__ pv_ws,
    float* __restrict__ se_ws, float* __restrict__ s0c_ws,
    float* __restrict__ stat_ws, int B)
{
  const int t = threadIdx.x, lane = t & 63, wv = t >> 6;
  const int b = blockIdx.x * 4 + wv;
  if (b >= B) return;
  const int c0 = lane * 4;

  const float* __restrict__ srow = storage + (size_t)b*KR*HIDV;
  float* __restrict__ urow = upd + (size_t)b*KR*HIDV;
  const float* __restrict__ qkp = qk_ws + (size_t)b*(NH*HIDV);

  const f4 qk0 = *reinterpret_cast<const f4*>(qkp + 0*HIDV + c0);
  const f4 qk1 = *reinterpret_cast<const f4*>(qkp + 1*HIDV + c0);
  const f4 qk2 = *reinterpret_cast<const f4*>(qkp + 2*HIDV + c0);
  const f4 qk3 = *reinterpret_cast<const f4*>(qkp + 3*HIDV + c0);
  const f4 msgr = *reinterpret_cast<const f4*>(msg + (size_t)b*HIDV + c0);

  {
    float a0 = red64f(dotf4(qk0, msgr));
    float a1 = red64f(dotf4(qk1, msgr));
    float a2 = red64f(dotf4(qk2, msgr));
    float a3 = red64f(dotf4(qk3, msgr));
    if (lane == 0) {
      s0c_ws[(size_t)b*NH + 0] = a0;
      s0c_ws[(size_t)b*NH + 1] = a1;
      s0c_ws[(size_t)b*NH + 2] = a2;
      s0c_ws[(size_t)b*NH + 3] = a3;
    }
  }

  f4 S1 = {0.f,0.f,0.f,0.f}, S2 = {0.f,0.f,0.f,0.f};
  f4 pv0 = {0.f,0.f,0.f,0.f}, pv1 = {0.f,0.f,0.f,0.f};
  f4 pv2 = {0.f,0.f,0.f,0.f}, pv3 = {0.f,0.f,0.f,0.f};
  float se0 = 0.f, se1 = 0.f, se2 = 0.f, se3 = 0.f;
  float cntf = 0.f;
  float dw = 1.f;

  f4 x[4], xn[4];
  #pragma unroll
  for (int rr = 0; rr < 4; ++rr)
    x[rr] = ntload4(srow + (size_t)rr*HIDV + c0);

  for (int g = 0; g < 16; ++g) {
    const int j0 = g*4;
    if (g < 15) {
      #pragma unroll
      for (int rr = 0; rr < 4; ++rr)
        xn[rr] = ntload4(srow + (size_t)(j0+4+rr)*HIDV + c0);
    }
    #pragma unroll
    for (int rr = 0; rr < 4; ++rr) {
      const int j = j0 + rr;
      f4 xx = x[rr];
      unsigned long long bal = __ballot(xx.x != 0.f || xx.y != 0.f ||
                                        xx.z != 0.f || xx.w != 0.f);
      if (bal) {
        cntf += 1.f;
        S1 += xx;
        S2 += xx*xx;
      }
      float sp0 = dotf4(qk0, xx);
      float sp1 = dotf4(qk1, xx);
      float sp2 = dotf4(qk2, xx);
      float sp3 = dotf4(qk3, xx);
      sp0 = red64f(sp0); sp1 = red64f(sp1);
      sp2 = red64f(sp2); sp3 = red64f(sp3);
      if (j < KR-1) {
        f4 u = xx * dw;
        *reinterpret_cast<f4*>(urow + (size_t)(j+1)*HIDV + c0) = u;  // normal store
        float f = dw * 0.125f;
        float e0 = __expf(sp0*f), e1 = __expf(sp1*f);
        float e2 = __expf(sp2*f), e3 = __expf(sp3*f);
        se0 += e0; se1 += e1; se2 += e2; se3 += e3;
        pv0 += xx * (e0*dw); pv1 += xx * (e1*dw);
        pv2 += xx * (e2*dw); pv3 += xx * (e3*dw);
      }
      dw *= 0.95f;
    }
    if (g < 15) {
      #pragma unroll
      for (int rr = 0; rr < 4; ++rr) x[rr] = xn[rr];
    }
  }

  const float msum = cntf + 1e-8f;
  const float inv = 1.f / msum;
  f4 mn;
  mn.x = S1.x*inv; mn.y = S1.y*inv; mn.z = S1.z*inv; mn.w = S1.w*inv;
  *reinterpret_cast<f4*>(mean_ws + (size_t)b*HIDV + c0) = mn;

  float ind = 0.f;
  {
    float vx = S2.x - 2.f*mn.x*S1.x + mn.x*mn.x*cntf;
    float vy = S2.y - 2.f*mn.y*S1.y + mn.y*mn.y*cntf;
    float vz = S2.z - 2.f*mn.z*S1.z + mn.z*mn.z*cntf;
    float vw = S2.w - 2.f*mn.w*S1.w + mn.w*mn.w*cntf;
    float sx = sqrtf(fmaxf(vx,0.f)*inv), sy = sqrtf(fmaxf(vy,0.f)*inv);
    float sz = sqrtf(fmaxf(vz,0.f)*inv), sw = sqrtf(fmaxf(vw,0.f)*inv);
    ind += (fabsf((msgr.x-mn.x)/(sx+1e-8f)) > 2.f) ? 1.f : 0.f;
    ind += (fabsf((msgr.y-mn.y)/(sy+1e-8f)) > 2.f) ? 1.f : 0.f;
    ind += (fabsf((msgr.z-mn.z)/(sz+1e-8f)) > 2.f) ? 1.f : 0.f;
    ind += (fabsf((msgr.w-mn.w)/(sw+1e-8f)) > 2.f) ? 1.f : 0.f;
  }
  ind = red64f(ind);

  float* pvp = pv_ws + (size_t)b*(NH*HIDV);
  *reinterpret_cast<f4*>(pvp + 0*HIDV + c0) = pv0;
  *reinterpret_cast<f4*>(pvp + 1*HIDV + c0) = pv1;
  *reinterpret_cast<f4*>(pvp + 2*HIDV + c0) = pv2;
  *reinterpret_cast<f4*>(pvp + 3*HIDV + c0) = pv3;

  if (lane == 0) {
    se_ws[(size_t)b*NH + 0] = se0;
    se_ws[(size_t)b*NH + 1] = se1;
    se_ws[(size_t)b*NH + 2] = se2;
    se_ws[(size_t)b*NH + 3] = se3;
    stat_ws[b] = ind * (1.f/256.f);
  }
}

// ---------------- K3 (MFMA): byte-identical R9 ----------------
__global__ __launch_bounds__(256) void k3_mfma(
    const unsigned short* __restrict__ msgb, const float* __restrict__ msg,
    const float* __restrict__ mean_ws, const float* __restrict__ pv_ws,
    const float* __restrict__ se_ws, const float* __restrict__ s0c_ws,
    const float* __restrict__ stat_ws, const float* __restrict__ la_ws,
    const float* __restrict__ b_im1, const float* __restrict__ w_im2,
    const float* __restrict__ b_im2, const float* __restrict__ ipb,
    const float* __restrict__ opb,
    const unsigned short* __restrict__ IM1F, const unsigned short* __restrict__ WVF,
    const unsigned short* __restrict__ OPF,
    float* __restrict__ upd, float* __restrict__ agg, int B)
{
  __shared__ float ctx_lds[16][260];
  __shared__ float part[4][16];
  __shared__ float imp_s[16];
  __shared__ float a0i_s[16][NH];
  __shared__ float inv_s[16][NH];
  const int t = threadIdx.x, l = t & 63, w = t >> 6;
  const int lr = l & 15, lk = l >> 4;
  const int b0 = blockIdx.x * 16;

  const unsigned short* arow = msgb + (size_t)(b0 + lr) * HIDV;
  const float* meanrow = mean_ws + (size_t)(b0 + lr) * HIDV;

  f4 ga[4];
  #pragma unroll
  for (int n = 0; n < 4; ++n) {
    float bi = b_im1[w*64 + n*16 + lr];
    f4 v = {bi, bi, bi, bi};
    ga[n] = v;
  }
  #pragma unroll
  for (int s = 0; s < 16; ++s) {
    bh8 a;
    if (s < 8) {
      a = *reinterpret_cast<const bh8*>(arow + s*32 + lk*8);
    } else {
      int k0 = (s-8)*32 + lk*8;
      f4 lo = *reinterpret_cast<const f4*>(meanrow + k0);
      f4 hi = *reinterpret_cast<const f4*>(meanrow + k0 + 4);
      a = cvt8(lo, hi);
    }
    #pragma unroll
    for (int n = 0; n < 4; ++n) {
      bh8 bw = *reinterpret_cast<const bh8*>(IM1F + (((size_t)(w*4+n)*16 + s)*64 + l)*8);
      ga[n] = MFMA16(a, bw, ga[n]);
    }
  }
  {
    float vv[4] = {0.f, 0.f, 0.f, 0.f};
    #pragma unroll
    for (int n = 0; n < 4; ++n) {
      float wi = w_im2[w*64 + n*16 + lr];
      #pragma unroll
      for (int qq = 0; qq < 4; ++qq)
        vv[qq] += fmaxf(ga[n][qq], 0.f) * wi;
    }
    #pragma unroll
    for (int m = 1; m < 16; m <<= 1) {
      #pragma unroll
      for (int qq = 0; qq < 4; ++qq) vv[qq] += __shfl_xor(vv[qq], m, 64);
    }
    if (lr == 0) {
      #pragma unroll
      for (int qq = 0; qq < 4; ++qq) part[w][lk*4+qq] = vv[qq];
    }
  }
  __syncthreads();
  if (t < 16) {
    float x = part[0][t]+part[1][t]+part[2][t]+part[3][t] + b_im2[0];
    float sp = fmaxf(x, 0.f) + log1pf(expf(-fabsf(x)));
    float an = 0.5f*stat_ws[b0+t] + 0.5f*la_ws[b0+t];
    imp_s[t] = sp * (1.f + an);
  }
  __syncthreads();

  if (t < 16*NH) {
    int r = t >> 2, h = t & 3;
    float impr = imp_s[r];
    float s0 = impr * s0c_ws[(size_t)(b0+r)*NH + h] * 0.125f;
    float e0 = __expf(s0);
    float invd = 1.f / (e0 + se_ws[(size_t)(b0+r)*NH + h]);
    a0i_s[r][h] = e0 * invd * impr;
    inv_s[r][h] = invd;
  }

  f4 vm[4], vp[4];
  #pragma unroll
  for (int n = 0; n < 4; ++n) { f4 z = {0.f,0.f,0.f,0.f}; vm[n] = z; vp[n] = z; }
  #pragma unroll
  for (int s = 0; s < 8; ++s) {
    bh8 a = *reinterpret_cast<const bh8*>(arow + s*32 + lk*8);
    #pragma unroll
    for (int n = 0; n < 4; ++n) {
      bh8 bw = *reinterpret_cast<const bh8*>(WVF + (((size_t)(w*4+n)*8 + s)*64 + l)*8);
      vm[n] = MFMA16(a, bw, vm[n]);
    }
  }
  {
    const float* pvrow = pv_ws + (size_t)(b0 + lr)*(NH*HIDV) + w*HIDV;
    #pragma unroll
    for (int s = 0; s < 8; ++s) {
      int k0 = s*32 + lk*8;
      f4 lo = *reinterpret_cast<const f4*>(pvrow + k0);
      f4 hi = *reinterpret_cast<const f4*>(pvrow + k0 + 4);
      bh8 a = cvt8(lo, hi);
      #pragma unroll
      for (int n = 0; n < 4; ++n) {
        bh8 bw = *reinterpret_cast<const bh8*>(WVF + (((size_t)(w*4+n)*8 + s)*64 + l)*8);
        vp[n] = MFMA16(a, bw, vp[n]);
      }
    }
  }
  __syncthreads();

  #pragma unroll
  for (int r = 0; r < 16; ++r)
    upd[(size_t)(b0+r)*KR*HIDV + t] = msg[(size_t)(b0+r)*HIDV + t] * imp_s[r];

  #pragma unroll
  for (int n = 0; n < 4; ++n) {
    float bv = ipb[2*HIDV + w*64 + n*16 + lr];
    #pragma unroll
    for (int qq = 0; qq < 4; ++qq) {
      int row = lk*4 + qq;
      ctx_lds[row][w*64 + n*16 + lr] = bv + a0i_s[row][w]*vm[n][qq] + inv_s[row][w]*vp[n][qq];
    }
  }
  __syncthreads();

  {
    f4 ag[4];
    #pragma unroll
    for (int n = 0; n < 4; ++n) {
      float bo = opb[w*64 + n*16 + lr];
      f4 v = {bo, bo, bo, bo};
      ag[n] = v;
    }
    const float* crow = &ctx_lds[lr][0];
    #pragma unroll
    for (int s = 0; s < 8; ++s) {
      int k0 = s*32 + lk*8;
      f4 lo = *reinterpret_cast<const f4*>(crow + k0);
      f4 hi = *reinterpret_cast<const f4*>(crow + k0 + 4);
      bh8 a = cvt8(lo, hi);
      #pragma unroll
      for (int n = 0; n < 4; ++n) {
        bh8 bw = *reinterpret_cast<const bh8*>(OPF + (((size_t)(w*4+n)*8 + s)*64 + l)*8);
        ag[n] = MFMA16(a, bw, ag[n]);
      }
    }
    #pragma unroll
    for (int n = 0; n < 4; ++n)
      #pragma unroll
      for (int qq = 0; qq < 4; ++qq)
        agg[(size_t)(b0 + lk*4 + qq)*HIDV + w*64 + n*16 + lr] = ag[n][qq];
  }
}

extern "C" void kernel_launch(void* const* d_in, const int* in_sizes, int n_in,
                              void* d_out, int out_size, void* d_ws, size_t ws_size,
                              hipStream_t stream) {
  const float* storage = (const float*)d_in[0];
  const float* msg     = (const float*)d_in[1];
  const float* w_ad1   = (const float*)d_in[2];
  const float* b_ad1   = (const float*)d_in[3];
  const float* w_ad2   = (const float*)d_in[4];
  const float* b_ad2   = (const float*)d_in[5];
  const float* w_im1   = (const float*)d_in[6];
  const float* b_im1   = (const float*)d_in[7];
  const float* w_im2   = (const float*)d_in[8];
  const float* b_im2   = (const float*)d_in[9];
  const float* ipw     = (const float*)d_in[10];
  const float* ipb     = (const float*)d_in[11];
  const float* opw     = (const float*)d_in[12];
  const float* opb     = (const float*)d_in[13];

  const int B = in_sizes[1] / HIDV;
  float* upd = (float*)d_out;
  float* agg = upd + (size_t)B*KR*HIDV;

  float* wsf = (float*)d_ws;
  size_t off = 0;
  float* qk    = wsf + off; off += (size_t)B*NH*HIDV;
  float* pv1   = wsf + off; off += (size_t)B*NH*HIDV;
  float* mean  = wsf + off; off += (size_t)B*HIDV;
  float* se1   = wsf + off; off += (size_t)B*NH;
  float* s0c   = wsf + off; off += (size_t)B*NH;
  float* stat  = wsf + off; off += (size_t)B;
  float* la    = wsf + off; off += (size_t)B;
  unsigned short* usb = (unsigned short*)(wsf + off);
  size_t uo = 0;
  unsigned short* msgb = usb + uo; uo += (size_t)B*HIDV;
  unsigned short* WQF  = usb + uo; uo += 65536;
  unsigned short* WKF  = usb + uo; uo += 65536;
  unsigned short* AD1F = usb + uo; uo += 32768;
  unsigned short* IM1F = usb + uo; uo += 131072;
  unsigned short* WVF  = usb + uo; uo += 65536;
  unsigned short* OPF  = usb + uo; uo += 65536;

  hipLaunchKernelGGL(k_prep_w, dim3(208), dim3(256), 0, stream,
                     ipw, w_ad1, w_im1, opw, WQF, WKF, AD1F, IM1F, WVF, OPF);
  hipLaunchKernelGGL(k_prep_msg, dim3((B*HIDV/8 + 255)/256), dim3(256), 0, stream,
                     msg, msgb, B*HIDV/8);
  hipLaunchKernelGGL(k0_mfma, dim3(B/16), dim3(256), 0, stream,
                     msgb, ipb, b_ad1, w_ad2, b_ad2, WQF, WKF, AD1F, qk, la, B);
  hipLaunchKernelGGL(k1_stream, dim3((B+3)/4), dim3(256), 0, stream,
                     storage, msg, qk, upd, mean, pv1, se1, s0c, stat, B);
  hipLaunchKernelGGL(k3_mfma, dim3(B/16), dim3(256), 0, stream,
                     msgb, msg, mean, pv1, se1, s0c, stat, la,
                     b_im1, w_im2, b_im2, ipb, opb,
                     IM1F, WVF, OPF, upd, agg, B);
}

// Round 11
// 282.337 us; speedup vs baseline: 1.0602x; 1.0602x over previous
//
#include <hip/hip_runtime.h>
#include <cstddef>
#include <cstdint>

#define HIDV 256
#define KR 64
#define NH 4

typedef float f4 __attribute__((ext_vector_type(4)));
typedef short bh8 __attribute__((ext_vector_type(8)));   // 8 bf16 (raw bits)
typedef unsigned int u32;

#define MFMA16(a,b,c) __builtin_amdgcn_mfma_f32_16x16x32_bf16(a,b,c,0,0,0)

__device__ __forceinline__ float dotf4(f4 a, f4 b) {
  return a.x*b.x + a.y*b.y + a.z*b.z + a.w*b.w;
}
__device__ __forceinline__ f4 ntload4(const float* p) {
  return __builtin_nontemporal_load(reinterpret_cast<const f4*>(p));
}
__device__ __forceinline__ void ntstore4(float* p, f4 v) {
  __builtin_nontemporal_store(v, reinterpret_cast<f4*>(p));
}
template<int CTRL>
__device__ __forceinline__ float dppadd(float v) {
  int m = __builtin_amdgcn_update_dpp(0, __float_as_int(v), CTRL, 0xf, 0xf, true);
  return v + __int_as_float(m);
}
__device__ __forceinline__ float red64f(float v) {
  v = dppadd<0xB1>(v);
  v = dppadd<0x4E>(v);
  v = dppadd<0x124>(v);
  v = dppadd<0x128>(v);
  v += __shfl_xor(v, 16);
  v += __shfl_xor(v, 32);
  return v;
}
__device__ __forceinline__ u32 pk2(float a, float b) {
  u32 r;
  asm("v_cvt_pk_bf16_f32 %0, %1, %2" : "=v"(r) : "v"(a), "v"(b));
  return r;
}
__device__ __forceinline__ bh8 cvt8(f4 lo, f4 hi) {
  union { bh8 b; u32 u[4]; } r;
  r.u[0] = pk2(lo.x, lo.y); r.u[1] = pk2(lo.z, lo.w);
  r.u[2] = pk2(hi.x, hi.y); r.u[3] = pk2(hi.z, hi.w);
  return r.b;
}

// ---------- prep: pack weights into MFMA B-fragment-linear bf16 ----------
__global__ __launch_bounds__(256) void k_prep_w(
    const float* __restrict__ ipw, const float* __restrict__ w_ad1,
    const float* __restrict__ w_im1, const float* __restrict__ opw,
    unsigned short* __restrict__ WQF, unsigned short* __restrict__ WKF,
    unsigned short* __restrict__ AD1F, unsigned short* __restrict__ IM1F,
    unsigned short* __restrict__ WVF, unsigned short* __restrict__ OPF)
{
  int f = blockIdx.x*256 + threadIdx.x;
  if (f >= 53248) return;
  const int l = f & 63, lr = l & 15, lk = l >> 4;
  int g = f >> 6;
  const float* src; unsigned short* dst; int stride; int gl;
  if (g < 128) {
    gl = g; int nt = g >> 3, s = g & 7;
    src = ipw + (size_t)(nt*16+lr)*256 + s*32 + lk*8; stride = 1; dst = WQF;
  } else if (g < 256) {
    gl = g - 128; int ntg = gl >> 1, s = gl & 1; int h = ntg >> 4, ntl = ntg & 15;
    src = ipw + 65536 + (size_t)(h*64 + s*32 + lk*8)*256 + ntl*16 + lr; stride = 256; dst = WKF;
  } else if (g < 320) {
    gl = g - 256; int nt = gl >> 3, s = gl & 7;
    src = w_ad1 + (size_t)(nt*16+lr)*256 + s*32 + lk*8; stride = 1; dst = AD1F;
  } else if (g < 576) {
    gl = g - 320; int nt = gl >> 4, s = gl & 15;
    src = w_im1 + (size_t)(nt*16+lr)*512 + s*32 + lk*8; stride = 1; dst = IM1F;
  } else if (g < 704) {
    gl = g - 576; int nt = gl >> 3, s = gl & 7;
    src = ipw + 131072 + (size_t)(nt*16+lr)*256 + s*32 + lk*8; stride = 1; dst = WVF;
  } else {
    gl = g - 704; int nt = gl >> 3, s = gl & 7;
    src = opw + (size_t)(nt*16+lr)*256 + s*32 + lk*8; stride = 1; dst = OPF;
  }
  float v[8];
  #pragma unroll
  for (int j = 0; j < 8; ++j) v[j] = src[(size_t)j*stride];
  union { bh8 b; u32 u[4]; } r;
  r.u[0] = pk2(v[0], v[1]); r.u[1] = pk2(v[2], v[3]);
  r.u[2] = pk2(v[4], v[5]); r.u[3] = pk2(v[6], v[7]);
  *reinterpret_cast<bh8*>(dst + ((size_t)gl*64 + l)*8) = r.b;
}

// ---------- prep: msg fp32 -> bf16 ----------
__global__ __launch_bounds__(256) void k_prep_msg(
    const float* __restrict__ msg, unsigned short* __restrict__ msgb, int n8)
{
  int i = blockIdx.x*256 + threadIdx.x;
  if (i >= n8) return;
  const float* p = msg + (size_t)i*8;
  f4 lo = *reinterpret_cast<const f4*>(p);
  f4 hi = *reinterpret_cast<const f4*>(p+4);
  union { bh8 b; u32 u[4]; } r;
  r.u[0] = pk2(lo.x, lo.y); r.u[1] = pk2(lo.z, lo.w);
  r.u[2] = pk2(hi.x, hi.y); r.u[3] = pk2(hi.z, hi.w);
  *reinterpret_cast<bh8*>(msgb + (size_t)i*8) = r.b;
}

// ---------------- K0 (MFMA): q, qk, learned anomaly ----------------
__global__ __launch_bounds__(256) void k0_mfma(
    const unsigned short* __restrict__ msgb,
    const float* __restrict__ ipb, const float* __restrict__ b_ad1,
    const float* __restrict__ w_ad2, const float* __restrict__ b_ad2,
    const unsigned short* __restrict__ WQF, const unsigned short* __restrict__ WKF,
    const unsigned short* __restrict__ AD1F,
    float* __restrict__ qk_ws, float* __restrict__ la_ws, int B)
{
  __shared__ float q_lds[16][260];
  __shared__ float part_ad[4][16];
  const int t = threadIdx.x, l = t & 63, w = t >> 6;
  const int lr = l & 15, lk = l >> 4;
  const int b0 = blockIdx.x * 16;

  const unsigned short* arow = msgb + (size_t)(b0 + lr) * HIDV;
  bh8 aM[8];
  #pragma unroll
  for (int s = 0; s < 8; ++s)
    aM[s] = *reinterpret_cast<const bh8*>(arow + s*32 + lk*8);

  f4 qa[4];
  #pragma unroll
  for (int n = 0; n < 4; ++n) {
    float bq = ipb[w*64 + n*16 + lr];
    f4 v = {bq, bq, bq, bq};
    qa[n] = v;
  }
  #pragma unroll
  for (int s = 0; s < 8; ++s) {
    #pragma unroll
    for (int n = 0; n < 4; ++n) {
      bh8 bw = *reinterpret_cast<const bh8*>(WQF + (((size_t)(w*4+n)*8 + s)*64 + l)*8);
      qa[n] = MFMA16(aM[s], bw, qa[n]);
    }
  }

  f4 ha[2];
  #pragma unroll
  for (int n = 0; n < 2; ++n) {
    float bb = b_ad1[w*32 + n*16 + lr];
    f4 v = {bb, bb, bb, bb};
    ha[n] = v;
  }
  #pragma unroll
  for (int s = 0; s < 8; ++s) {
    #pragma unroll
    for (int n = 0; n < 2; ++n) {
      bh8 bw = *reinterpret_cast<const bh8*>(AD1F + (((size_t)(w*2+n)*8 + s)*64 + l)*8);
      ha[n] = MFMA16(aM[s], bw, ha[n]);
    }
  }

  #pragma unroll
  for (int n = 0; n < 4; ++n)
    #pragma unroll
    for (int qq = 0; qq < 4; ++qq)
      q_lds[lk*4+qq][w*64 + n*16 + lr] = qa[n][qq];

  {
    float wa0 = w_ad2[w*32 + lr];
    float wa1 = w_ad2[w*32 + 16 + lr];
    float vv[4];
    #pragma unroll
    for (int qq = 0; qq < 4; ++qq)
      vv[qq] = fmaxf(ha[0][qq], 0.f)*wa0 + fmaxf(ha[1][qq], 0.f)*wa1;
    #pragma unroll
    for (int m = 1; m < 16; m <<= 1) {
      #pragma unroll
      for (int qq = 0; qq < 4; ++qq) vv[qq] += __shfl_xor(vv[qq], m, 64);
    }
    if (lr == 0) {
      #pragma unroll
      for (int qq = 0; qq < 4; ++qq) part_ad[w][lk*4+qq] = vv[qq];
    }
  }
  __syncthreads();
  if (t < 16) {
    float x = part_ad[0][t]+part_ad[1][t]+part_ad[2][t]+part_ad[3][t] + b_ad2[0];
    la_ws[b0 + t] = 1.f / (1.f + expf(-x));
  }

  const float* qrow = &q_lds[lr][0];
  for (int h = 0; h < NH; ++h) {
    f4 ka[4];
    #pragma unroll
    for (int n = 0; n < 4; ++n) { f4 z = {0.f,0.f,0.f,0.f}; ka[n] = z; }
    #pragma unroll
    for (int s2 = 0; s2 < 2; ++s2) {
      int k0 = h*64 + s2*32 + lk*8;
      f4 lo = *reinterpret_cast<const f4*>(qrow + k0);
      f4 hi = *reinterpret_cast<const f4*>(qrow + k0 + 4);
      bh8 aQ = cvt8(lo, hi);
      #pragma unroll
      for (int n = 0; n < 4; ++n) {
        bh8 bw = *reinterpret_cast<const bh8*>(WKF + (((size_t)((h*16 + w*4+n)*2 + s2))*64 + l)*8);
        ka[n] = MFMA16(aQ, bw, ka[n]);
      }
    }
    #pragma unroll
    for (int n = 0; n < 4; ++n)
      #pragma unroll
      for (int qq = 0; qq < 4; ++qq)
        qk_ws[(size_t)(b0 + lk*4 + qq)*(NH*HIDV) + h*HIDV + w*64 + n*16 + lr] = ka[n][qq];
  }
}

// ---------------- K1: one wave per b, NT loads + NT stores (best config, R9) ----------------
__global__ __launch_bounds__(256) void k1_stream(
    const float* __restrict__ storage, const float* __restrict__ msg,
    const float* __restrict__ qk_ws,
    float* __restrict__ upd,
    float* __restrict__ mean_ws, float* __restrict__ pv_ws,
    float* __restrict__ se_ws, float* __restrict__ s0c_ws,
    float* __restrict__ stat_ws, int B)
{
  const int t = threadIdx.x, lane = t & 63, wv = t >> 6;
  const int b = blockIdx.x * 4 + wv;
  if (b >= B) return;
  const int c0 = lane * 4;

  const float* __restrict__ srow = storage + (size_t)b*KR*HIDV;
  float* __restrict__ urow = upd + (size_t)b*KR*HIDV;
  const float* __restrict__ qkp = qk_ws + (size_t)b*(NH*HIDV);

  const f4 qk0 = *reinterpret_cast<const f4*>(qkp + 0*HIDV + c0);
  const f4 qk1 = *reinterpret_cast<const f4*>(qkp + 1*HIDV + c0);
  const f4 qk2 = *reinterpret_cast<const f4*>(qkp + 2*HIDV + c0);
  const f4 qk3 = *reinterpret_cast<const f4*>(qkp + 3*HIDV + c0);
  const f4 msgr = *reinterpret_cast<const f4*>(msg + (size_t)b*HIDV + c0);

  {
    float a0 = red64f(dotf4(qk0, msgr));
    float a1 = red64f(dotf4(qk1, msgr));
    float a2 = red64f(dotf4(qk2, msgr));
    float a3 = red64f(dotf4(qk3, msgr));
    if (lane == 0) {
      s0c_ws[(size_t)b*NH + 0] = a0;
      s0c_ws[(size_t)b*NH + 1] = a1;
      s0c_ws[(size_t)b*NH + 2] = a2;
      s0c_ws[(size_t)b*NH + 3] = a3;
    }
  }

  f4 S1 = {0.f,0.f,0.f,0.f}, S2 = {0.f,0.f,0.f,0.f};
  f4 pv0 = {0.f,0.f,0.f,0.f}, pv1 = {0.f,0.f,0.f,0.f};
  f4 pv2 = {0.f,0.f,0.f,0.f}, pv3 = {0.f,0.f,0.f,0.f};
  float se0 = 0.f, se1 = 0.f, se2 = 0.f, se3 = 0.f;
  float cntf = 0.f;
  float dw = 1.f;

  f4 x[4], xn[4];
  #pragma unroll
  for (int rr = 0; rr < 4; ++rr)
    x[rr] = ntload4(srow + (size_t)rr*HIDV + c0);

  for (int g = 0; g < 16; ++g) {
    const int j0 = g*4;
    if (g < 15) {
      #pragma unroll
      for (int rr = 0; rr < 4; ++rr)
        xn[rr] = ntload4(srow + (size_t)(j0+4+rr)*HIDV + c0);
    }
    #pragma unroll
    for (int rr = 0; rr < 4; ++rr) {
      const int j = j0 + rr;
      f4 xx = x[rr];
      unsigned long long bal = __ballot(xx.x != 0.f || xx.y != 0.f ||
                                        xx.z != 0.f || xx.w != 0.f);
      if (bal) {
        cntf += 1.f;
        S1 += xx;
        S2 += xx*xx;
      }
      float sp0 = dotf4(qk0, xx);
      float sp1 = dotf4(qk1, xx);
      float sp2 = dotf4(qk2, xx);
      float sp3 = dotf4(qk3, xx);
      sp0 = red64f(sp0); sp1 = red64f(sp1);
      sp2 = red64f(sp2); sp3 = red64f(sp3);
      if (j < KR-1) {
        f4 u = xx * dw;
        ntstore4(urow + (size_t)(j+1)*HIDV + c0, u);
        float f = dw * 0.125f;
        float e0 = __expf(sp0*f), e1 = __expf(sp1*f);
        float e2 = __expf(sp2*f), e3 = __expf(sp3*f);
        se0 += e0; se1 += e1; se2 += e2; se3 += e3;
        pv0 += xx * (e0*dw); pv1 += xx * (e1*dw);
        pv2 += xx * (e2*dw); pv3 += xx * (e3*dw);
      }
      dw *= 0.95f;
    }
    if (g < 15) {
      #pragma unroll
      for (int rr = 0; rr < 4; ++rr) x[rr] = xn[rr];
    }
  }

  const float msum = cntf + 1e-8f;
  const float inv = 1.f / msum;
  f4 mn;
  mn.x = S1.x*inv; mn.y = S1.y*inv; mn.z = S1.z*inv; mn.w = S1.w*inv;
  *reinterpret_cast<f4*>(mean_ws + (size_t)b*HIDV + c0) = mn;

  float ind = 0.f;
  {
    float vx = S2.x - 2.f*mn.x*S1.x + mn.x*mn.x*cntf;
    float vy = S2.y - 2.f*mn.y*S1.y + mn.y*mn.y*cntf;
    float vz = S2.z - 2.f*mn.z*S1.z + mn.z*mn.z*cntf;
    float vw = S2.w - 2.f*mn.w*S1.w + mn.w*mn.w*cntf;
    float sx = sqrtf(fmaxf(vx,0.f)*inv), sy = sqrtf(fmaxf(vy,0.f)*inv);
    float sz = sqrtf(fmaxf(vz,0.f)*inv), sw = sqrtf(fmaxf(vw,0.f)*inv);
    ind += (fabsf((msgr.x-mn.x)/(sx+1e-8f)) > 2.f) ? 1.f : 0.f;
    ind += (fabsf((msgr.y-mn.y)/(sy+1e-8f)) > 2.f) ? 1.f : 0.f;
    ind += (fabsf((msgr.z-mn.z)/(sz+1e-8f)) > 2.f) ? 1.f : 0.f;
    ind += (fabsf((msgr.w-mn.w)/(sw+1e-8f)) > 2.f) ? 1.f : 0.f;
  }
  ind = red64f(ind);

  float* pvp = pv_ws + (size_t)b*(NH*HIDV);
  *reinterpret_cast<f4*>(pvp + 0*HIDV + c0) = pv0;
  *reinterpret_cast<f4*>(pvp + 1*HIDV + c0) = pv1;
  *reinterpret_cast<f4*>(pvp + 2*HIDV + c0) = pv2;
  *reinterpret_cast<f4*>(pvp + 3*HIDV + c0) = pv3;

  if (lane == 0) {
    se_ws[(size_t)b*NH + 0] = se0;
    se_ws[(size_t)b*NH + 1] = se1;
    se_ws[(size_t)b*NH + 2] = se2;
    se_ws[(size_t)b*NH + 3] = se3;
    stat_ws[b] = ind * (1.f/256.f);
  }
}

// ---------------- K3 (MFMA): im1/imp, row0, ctx, out proj ----------------
__global__ __launch_bounds__(256) void k3_mfma(
    const unsigned short* __restrict__ msgb, const float* __restrict__ msg,
    const float* __restrict__ mean_ws, const float* __restrict__ pv_ws,
    const float* __restrict__ se_ws, const float* __restrict__ s0c_ws,
    const float* __restrict__ stat_ws, const float* __restrict__ la_ws,
    const float* __restrict__ b_im1, const float* __restrict__ w_im2,
    const float* __restrict__ b_im2, const float* __restrict__ ipb,
    const float* __restrict__ opb,
    const unsigned short* __restrict__ IM1F, const unsigned short* __restrict__ WVF,
    const unsigned short* __restrict__ OPF,
    float* __restrict__ upd, float* __restrict__ agg, int B)
{
  __shared__ float ctx_lds[16][260];
  __shared__ float part[4][16];
  __shared__ float imp_s[16];
  __shared__ float a0i_s[16][NH];
  __shared__ float inv_s[16][NH];
  const int t = threadIdx.x, l = t & 63, w = t >> 6;
  const int lr = l & 15, lk = l >> 4;
  const int b0 = blockIdx.x * 16;

  const unsigned short* arow = msgb + (size_t)(b0 + lr) * HIDV;
  const float* meanrow = mean_ws + (size_t)(b0 + lr) * HIDV;

  f4 ga[4];
  #pragma unroll
  for (int n = 0; n < 4; ++n) {
    float bi = b_im1[w*64 + n*16 + lr];
    f4 v = {bi, bi, bi, bi};
    ga[n] = v;
  }
  #pragma unroll
  for (int s = 0; s < 16; ++s) {
    bh8 a;
    if (s < 8) {
      a = *reinterpret_cast<const bh8*>(arow + s*32 + lk*8);
    } else {
      int k0 = (s-8)*32 + lk*8;
      f4 lo = *reinterpret_cast<const f4*>(meanrow + k0);
      f4 hi = *reinterpret_cast<const f4*>(meanrow + k0 + 4);
      a = cvt8(lo, hi);
    }
    #pragma unroll
    for (int n = 0; n < 4; ++n) {
      bh8 bw = *reinterpret_cast<const bh8*>(IM1F + (((size_t)(w*4+n)*16 + s)*64 + l)*8);
      ga[n] = MFMA16(a, bw, ga[n]);
    }
  }
  {
    float vv[4] = {0.f, 0.f, 0.f, 0.f};
    #pragma unroll
    for (int n = 0; n < 4; ++n) {
      float wi = w_im2[w*64 + n*16 + lr];
      #pragma unroll
      for (int qq = 0; qq < 4; ++qq)
        vv[qq] += fmaxf(ga[n][qq], 0.f) * wi;
    }
    #pragma unroll
    for (int m = 1; m < 16; m <<= 1) {
      #pragma unroll
      for (int qq = 0; qq < 4; ++qq) vv[qq] += __shfl_xor(vv[qq], m, 64);
    }
    if (lr == 0) {
      #pragma unroll
      for (int qq = 0; qq < 4; ++qq) part[w][lk*4+qq] = vv[qq];
    }
  }
  __syncthreads();
  if (t < 16) {
    float x = part[0][t]+part[1][t]+part[2][t]+part[3][t] + b_im2[0];
    float sp = fmaxf(x, 0.f) + log1pf(expf(-fabsf(x)));
    float an = 0.5f*stat_ws[b0+t] + 0.5f*la_ws[b0+t];
    imp_s[t] = sp * (1.f + an);
  }
  __syncthreads();

  if (t < 16*NH) {
    int r = t >> 2, h = t & 3;
    float impr = imp_s[r];
    float s0 = impr * s0c_ws[(size_t)(b0+r)*NH + h] * 0.125f;
    float e0 = __expf(s0);
    float invd = 1.f / (e0 + se_ws[(size_t)(b0+r)*NH + h]);
    a0i_s[r][h] = e0 * invd * impr;
    inv_s[r][h] = invd;
  }

  f4 vm[4], vp[4];
  #pragma unroll
  for (int n = 0; n < 4; ++n) { f4 z = {0.f,0.f,0.f,0.f}; vm[n] = z; vp[n] = z; }
  #pragma unroll
  for (int s = 0; s < 8; ++s) {
    bh8 a = *reinterpret_cast<const bh8*>(arow + s*32 + lk*8);
    #pragma unroll
    for (int n = 0; n < 4; ++n) {
      bh8 bw = *reinterpret_cast<const bh8*>(WVF + (((size_t)(w*4+n)*8 + s)*64 + l)*8);
      vm[n] = MFMA16(a, bw, vm[n]);
    }
  }
  {
    const float* pvrow = pv_ws + (size_t)(b0 + lr)*(NH*HIDV) + w*HIDV;
    #pragma unroll
    for (int s = 0; s < 8; ++s) {
      int k0 = s*32 + lk*8;
      f4 lo = *reinterpret_cast<const f4*>(pvrow + k0);
      f4 hi = *reinterpret_cast<const f4*>(pvrow + k0 + 4);
      bh8 a = cvt8(lo, hi);
      #pragma unroll
      for (int n = 0; n < 4; ++n) {
        bh8 bw = *reinterpret_cast<const bh8*>(WVF + (((size_t)(w*4+n)*8 + s)*64 + l)*8);
        vp[n] = MFMA16(a, bw, vp[n]);
      }
    }
  }
  __syncthreads();

  #pragma unroll
  for (int r = 0; r < 16; ++r)
    upd[(size_t)(b0+r)*KR*HIDV + t] = msg[(size_t)(b0+r)*HIDV + t] * imp_s[r];

  #pragma unroll
  for (int n = 0; n < 4; ++n) {
    float bv = ipb[2*HIDV + w*64 + n*16 + lr];
    #pragma unroll
    for (int qq = 0; qq < 4; ++qq) {
      int row = lk*4 + qq;
      ctx_lds[row][w*64 + n*16 + lr] = bv + a0i_s[row][w]*vm[n][qq] + inv_s[row][w]*vp[n][qq];
    }
  }
  __syncthreads();

  {
    f4 ag[4];
    #pragma unroll
    for (int n = 0; n < 4; ++n) {
      float bo = opb[w*64 + n*16 + lr];
      f4 v = {bo, bo, bo, bo};
      ag[n] = v;
    }
    const float* crow = &ctx_lds[lr][0];
    #pragma unroll
    for (int s = 0; s < 8; ++s) {
      int k0 = s*32 + lk*8;
      f4 lo = *reinterpret_cast<const f4*>(crow + k0);
      f4 hi = *reinterpret_cast<const f4*>(crow + k0 + 4);
      bh8 a = cvt8(lo, hi);
      #pragma unroll
      for (int n = 0; n < 4; ++n) {
        bh8 bw = *reinterpret_cast<const bh8*>(OPF + (((size_t)(w*4+n)*8 + s)*64 + l)*8);
        ag[n] = MFMA16(a, bw, ag[n]);
      }
    }
    #pragma unroll
    for (int n = 0; n < 4; ++n)
      #pragma unroll
      for (int qq = 0; qq < 4; ++qq)
        agg[(size_t)(b0 + lk*4 + qq)*HIDV + w*64 + n*16 + lr] = ag[n][qq];
  }
}

extern "C" void kernel_launch(void* const* d_in, const int* in_sizes, int n_in,
                              void* d_out, int out_size, void* d_ws, size_t ws_size,
                              hipStream_t stream) {
  const float* storage = (const float*)d_in[0];
  const float* msg     = (const float*)d_in[1];
  const float* w_ad1   = (const float*)d_in[2];
  const float* b_ad1   = (const float*)d_in[3];
  const float* w_ad2   = (const float*)d_in[4];
  const float* b_ad2   = (const float*)d_in[5];
  const float* w_im1   = (const float*)d_in[6];
  const float* b_im1   = (const float*)d_in[7];
  const float* w_im2   = (const float*)d_in[8];
  const float* b_im2   = (const float*)d_in[9];
  const float* ipw     = (const float*)d_in[10];
  const float* ipb     = (const float*)d_in[11];
  const float* opw     = (const float*)d_in[12];
  const float* opb     = (const float*)d_in[13];

  const int B = in_sizes[1] / HIDV;
  float* upd = (float*)d_out;
  float* agg = upd + (size_t)B*KR*HIDV;

  float* wsf = (float*)d_ws;
  size_t off = 0;
  float* qk    = wsf + off; off += (size_t)B*NH*HIDV;
  float* pv1   = wsf + off; off += (size_t)B*NH*HIDV;
  float* mean  = wsf + off; off += (size_t)B*HIDV;
  float* se1   = wsf + off; off += (size_t)B*NH;
  float* s0c   = wsf + off; off += (size_t)B*NH;
  float* stat  = wsf + off; off += (size_t)B;
  float* la    = wsf + off; off += (size_t)B;
  unsigned short* usb = (unsigned short*)(wsf + off);
  size_t uo = 0;
  unsigned short* msgb = usb + uo; uo += (size_t)B*HIDV;
  unsigned short* WQF  = usb + uo; uo += 65536;
  unsigned short* WKF  = usb + uo; uo += 65536;
  unsigned short* AD1F = usb + uo; uo += 32768;
  unsigned short* IM1F = usb + uo; uo += 131072;
  unsigned short* WVF  = usb + uo; uo += 65536;
  unsigned short* OPF  = usb + uo; uo += 65536;

  hipLaunchKernelGGL(k_prep_w, dim3(208), dim3(256), 0, stream,
                     ipw, w_ad1, w_im1, opw, WQF, WKF, AD1F, IM1F, WVF, OPF);
  hipLaunchKernelGGL(k_prep_msg, dim3((B*HIDV/8 + 255)/256), dim3(256), 0, stream,
                     msg, msgb, B*HIDV/8);
  hipLaunchKernelGGL(k0_mfma, dim3(B/16), dim3(256), 0, stream,
                     msgb, ipb, b_ad1, w_ad2, b_ad2, WQF, WKF, AD1F, qk, la, B);
  hipLaunchKernelGGL(k1_stream, dim3((B+3)/4), dim3(256), 0, stream,
                     storage, msg, qk, upd, mean, pv1, se1, s0c, stat, B);
  hipLaunchKernelGGL(k3_mfma, dim3(B/16), dim3(256), 0, stream,
                     msgb, msg, mean, pv1, se1, s0c, stat, la,
                     b_im1, w_im2, b_im2, ipb, opb,
                     IM1F, WVF, OPF, upd, agg, B);
}